// Round 2
// baseline (118.478 us; speedup 1.0000x reference)
//
#include <hip/hip_runtime.h>

#define B_AGENTS 262144
#define NN 17
#define BLOCK 256
#define CHUNK (BLOCK * NN)          // 4352 floats = 17408 B per matrix per block
#define CHUNK4 (CHUNK / 4)          // 1088 float4s

__global__ __launch_bounds__(BLOCK) void grossberg_kernel(
    const float* __restrict__ state,
    const float* __restrict__ W_pos,
    const float* __restrict__ W_neg,
    const float* __restrict__ feas,
    const float* __restrict__ pert,
    float* __restrict__ out)
{
    __shared__ float lwp[CHUNK];
    __shared__ float lwn[CHUNK];

    const int tid = threadIdx.x;
    const size_t base = (size_t)blockIdx.x * CHUNK;

    // --- coalesced float4 staging of this block's 256 contiguous W rows ---
    const float4* __restrict__ gp = (const float4*)(W_pos + base);
    const float4* __restrict__ gn = (const float4*)(W_neg + base);
    float4* lp = (float4*)lwp;
    float4* ln = (float4*)lwn;
    #pragma unroll
    for (int it = 0; it < 4; ++it) {            // 4 × 256 = 1024 float4s
        const int k = tid + it * BLOCK;
        lp[k] = gp[k];
        ln[k] = gn[k];
    }
    if (tid < CHUNK4 - 4 * BLOCK) {             // tail: 64 float4s
        const int k = tid + 4 * BLOCK;
        lp[k] = gp[k];
        ln[k] = gn[k];
    }

    // --- per-thread (agent, row) mapping ---
    const int t = blockIdx.x * BLOCK + tid;     // grid covers exactly B*NN
    const int b = t / NN;                       // magic-multiply
    const int i = t - b * NN;

    // agent state vector: lanes cluster into ~5 lines/instr -> cheap via L1
    float sv[NN];
    const float* __restrict__ s = state + b * NN;
    #pragma unroll
    for (int j = 0; j < NN; ++j) sv[j] = s[j];

    __syncthreads();

    // --- two matvec rows from LDS (17l+j mod 32 -> 2 lanes/bank, conflict-free)
    const float* wpr = lwp + tid * NN;
    const float* wnr = lwn + tid * NN;
    float sum_p = 0.f, sum_n = 0.f;
    #pragma unroll
    for (int j = 0; j < NN; ++j) {
        sum_p = fmaf(wpr[j], sv[j], sum_p);
        sum_n = fmaf(wnr[j], sv[j], sum_n);
    }

    // --- gating / env / lateral / mask ---
    float gate_e = 1.f, gate_i = 1.f;
    float env_e = 0.f, env_i = 0.f;
    float lat = 0.f, mask = 1.f;

    if (i < 9) {
        const float p = pert[b * NN + i];
        env_e = fmaxf(p, 0.f);
        env_i = fmaxf(-p, 0.f);
    } else if (i < 13) {
        const float v = sv[i + 4] + pert[b * NN + i + 4];   // valences_eval[i-9]
        gate_e = 1.f / (1.f + __expf(-1.5f * v));           // sigmoid(ALPHA*v)
        gate_i = 1.f / (1.f + __expf(0.75f * v));           // sigmoid(-BETA*v)
        const float sum_act = sv[9] + sv[10] + sv[11] + sv[12];
        const float other = sum_act - sv[i];
        lat = 3.0f * other / (0.3f + other + 1e-6f);        // LAT_INHIB/(DIV_SIGMA+..)
        mask = feas[b * 4 + (i - 9)];
    }

    const float te = gate_e * sum_p + env_e;
    const float ti = gate_i * sum_n + lat + env_i;
    const float si = sv[i];

    const float dS = (-0.15f * si
                      + (1.0f - si) * fmaxf(te, 0.f)
                      - (0.1f + si) * fmaxf(ti, 0.f)) * 1.25f;   // /TAU

    out[t] = dS * mask;
}

extern "C" void kernel_launch(void* const* d_in, const int* in_sizes, int n_in,
                              void* d_out, int out_size, void* d_ws, size_t ws_size,
                              hipStream_t stream)
{
    // setup_inputs order: t, state, W_pos, W_neg, feasibility, perturbation
    const float* state = (const float*)d_in[1];
    const float* W_pos = (const float*)d_in[2];
    const float* W_neg = (const float*)d_in[3];
    const float* feas  = (const float*)d_in[4];
    const float* pert  = (const float*)d_in[5];
    float* out = (float*)d_out;

    const int total = B_AGENTS * NN;            // 4456448, divisible by 256
    const int grid = total / BLOCK;             // 17408 blocks
    grossberg_kernel<<<grid, BLOCK, 0, stream>>>(state, W_pos, W_neg, feas, pert, out);
}